// Round 9
// baseline (125.205 us; speedup 1.0000x reference)
//
#include <hip/hip_runtime.h>

#define HH 4096
#define WW 4096
#define KK 256
#define RMAX 10
#define DD 21
#define NSQ (DD * DD)              // 441
#define MAXTOUCH (KK * NSQ)        // 112896

#define NB  8192                   // blocks for dense kernels
#define TPB 256
#define NT  (NB * TPB)             // 2097152 float4-slots per stream half
#define NWAVES (NT / 64)           // 32768
#define RB1 128                    // reduce stage-1 blocks
#define GSB 2048                   // grid-stride probe blocks

typedef float vfloat4 __attribute__((ext_vector_type(4)));

// d_ws layout (bytes):
#define FIX_OFF   0                      // double fix_delta[KK]       (2048 B)
#define P2SF_OFF  4096                   // double part2_sf[RB1]       (1024 B)
#define P2SU_OFF  8192                   // double part2_su[RB1]       (1024 B)
#define SCALE_OFF 12288                  // float  scale
#define WSF_OFF   16384                  // float  wave_sf[NWAVES]     (131072 B)
#define WSU_OFF   (16384 + 131072)       // float  wave_su[NWAVES]     (131072 B)
#define LIDX_OFF  (WSU_OFF + 131072)     // int    list_idx[MAXTOUCH]  (451584 B)
#define LFU_OFF   (LIDX_OFF + 451584)    // float  list_fu[MAXTOUCH]

// ================= PROBES (diagnostic; sinks overwritten by pipeline) ======

// P0: dispatch-rate control. 8192 blocks, no dense memory work.
__global__ void __launch_bounds__(TPB) probe_null(float* __restrict__ sink) {
    if (threadIdx.x == 0) sink[blockIdx.x] = (float)blockIdx.x;
}

// P1: single-stream read (64 MB), same structure/epilogue as norms2.
__global__ void __launch_bounds__(TPB) probe_f(const float* __restrict__ field,
                                               float* __restrict__ sink) {
    const int tid = blockIdx.x * TPB + threadIdx.x;
    const float4* __restrict__ F = (const float4*)field;
    float4 a = F[tid], b = F[tid + NT];
    float s = a.x*a.x + a.y*a.y + a.z*a.z + a.w*a.w
            + b.x*b.x + b.y*b.y + b.z*b.z + b.w*b.w;
    #pragma unroll
    for (int off = 32; off > 0; off >>= 1) s += __shfl_down(s, off);
    if ((threadIdx.x & 63) == 0) sink[tid >> 6] = s;
}

// P2: dual-stream read (128 MB) with signal's addresses shifted +16 MB
// (mod stream) to decorrelate simultaneous channel targets. Unpaired (probe).
__global__ void __launch_bounds__(TPB) probe_shift(const float* __restrict__ field,
                                                   const float* __restrict__ signal,
                                                   float* __restrict__ sink) {
    const int tid = blockIdx.x * TPB + threadIdx.x;
    const int gt  = (tid + NT / 2) & (NT - 1);
    const float4* __restrict__ F = (const float4*)field;
    const float4* __restrict__ G = (const float4*)signal;
    float4 a = F[tid], b = F[tid + NT];
    float4 c = G[gt],  d = G[gt + NT];
    float s = a.x*a.x + a.y*a.y + a.z*a.z + a.w*a.w
            + b.x*b.x + b.y*b.y + b.z*b.z + b.w*b.w
            + c.x*c.x + c.y*c.y + c.z*c.z + c.w*c.w
            + d.x*d.x + d.y*d.y + d.z*d.z + d.w*d.w;
    #pragma unroll
    for (int off = 32; off > 0; off >>= 1) s += __shfl_down(s, off);
    if ((threadIdx.x & 63) == 0) sink[tid >> 6] = s;
}

// P3: dual-stream paired (128 MB), 2048 blocks, grid-stride 8 iters
// (m13 copy shape: long-lived waves, dispatch amortized).
__global__ void __launch_bounds__(TPB) probe_gs(const float* __restrict__ field,
                                                const float* __restrict__ signal,
                                                float* __restrict__ sink) {
    const int tid0 = blockIdx.x * TPB + threadIdx.x;
    const float4* __restrict__ F = (const float4*)field;
    const float4* __restrict__ G = (const float4*)signal;
    float s = 0.0f;
    for (int i = tid0; i < HH * WW / 4; i += GSB * TPB) {
        float4 f = F[i];
        float4 g = G[i];
        s += f.x*f.x + f.y*f.y + f.z*f.z + f.w*f.w
           + g.x*g.x + g.y*g.y + g.z*g.z + g.w*g.w;
    }
    #pragma unroll
    for (int off = 32; off > 0; off >>= 1) s += __shfl_down(s, off);
    if ((threadIdx.x & 63) == 0) sink[(tid0 >> 6)] = s;
}

// ================= PIPELINE (unchanged from R8, passing) ===================

__global__ void ecli_clear(const int* __restrict__ pos, float* __restrict__ addmap) {
    const int k = blockIdx.x;
    const int t = threadIdx.x;
    if (t >= NSQ) return;
    const int ni = pos[2 * k + 0] + t / DD - RMAX;
    const int nj = pos[2 * k + 1] + t % DD - RMAX;
    if (ni < 0 || ni >= HH || nj < 0 || nj >= WW) return;
    addmap[(size_t)ni * WW + nj] = 0.0f;
}

__global__ void ecli_scatter(const int* __restrict__ pos,
                             const float* __restrict__ strength,
                             const float* __restrict__ local_ratio,
                             float* __restrict__ addmap) {
    const int k = blockIdx.x;
    const int t = threadIdx.x;
    if (t >= NSQ) return;
    const float s   = strength[k];
    const float lr  = *local_ratio;
    const float rad = floorf(5.0f * s);
    const float inv = -0.5f / (4.0f * s * s);
    const float amp = lr * s;
    const int di = t / DD - RMAX;
    const int dj = t % DD - RMAX;
    if (fabsf((float)di) > rad || fabsf((float)dj) > rad) return;
    const int ni = pos[2 * k + 0] + di;
    const int nj = pos[2 * k + 1] + dj;
    if (ni < 0 || ni >= HH || nj < 0 || nj >= WW) return;
    const float c = expf((float)(di * di + dj * dj) * inv) * amp;
    atomicAdd(&addmap[(size_t)ni * WW + nj], c);
}

__global__ void ecli_fixup(const int* __restrict__ pos,
                           const float* __restrict__ field,
                           const float* __restrict__ signal,
                           const float* __restrict__ gratio,
                           const float* __restrict__ infl,
                           float* __restrict__ addmap,
                           int* __restrict__ list_idx,
                           float* __restrict__ list_fu,
                           double* __restrict__ fix_delta) {
    const int k = blockIdx.x;
    const int t = threadIdx.x;
    double delta = 0.0;
    if (t < NSQ) {
        int out_idx = -1;
        float out_fu = 0.0f;
        const int ni = pos[2 * k + 0] + t / DD - RMAX;
        const int nj = pos[2 * k + 1] + t % DD - RMAX;
        if (ni >= 0 && ni < HH && nj >= 0 && nj < WW) {
            const size_t idx = (size_t)ni * WW + nj;
            const float val = atomicExch(&addmap[idx], 0.0f);
            if (val != 0.0f) {
                const float gr = *gratio;
                const float is = *infl;
                const float f = field[idx];
                const float g = signal[idx];
                const float m0 = is / (1.0f + expf(-gr));
                const float m1 = is / (1.0f + expf(-(gr + val)));
                const float fu0 = fmaf(g - f, m0, f);
                const float fu1 = fmaf(g - f, m1, f);
                out_idx = (int)idx;
                out_fu  = fu1;
                delta = (double)fu1 * (double)fu1 - (double)fu0 * (double)fu0;
            }
        }
        list_idx[k * NSQ + t] = out_idx;
        list_fu [k * NSQ + t] = out_fu;
    }
    __shared__ double sred[7];
    #pragma unroll
    for (int off = 32; off > 0; off >>= 1) delta += __shfl_down(delta, off);
    if ((t & 63) == 0) sred[t >> 6] = delta;
    __syncthreads();
    if (t == 0) {
        double d = 0.0;
        #pragma unroll
        for (int i = 0; i < 7; ++i) d += sred[i];
        fix_delta[k] = d;
    }
}

__global__ void __launch_bounds__(TPB) ecli_norms2(
        const float* __restrict__ field,
        const float* __restrict__ signal,
        const float* __restrict__ gratio,
        const float* __restrict__ infl,
        float* __restrict__ wave_sf,
        float* __restrict__ wave_su) {
    const int tid = blockIdx.x * TPB + threadIdx.x;
    const float gr = *gratio;
    const float is = *infl;
    const float m0 = is / (1.0f + expf(-gr));
    const float4* __restrict__ F = (const float4*)field;
    const float4* __restrict__ G = (const float4*)signal;

    float4 f0 = F[tid];
    float4 f1 = F[tid + NT];
    float4 g0 = G[tid];
    float4 g1 = G[tid + NT];

    float sf = 0.0f, su = 0.0f;
    float r;
    sf += f0.x*f0.x + f0.y*f0.y + f0.z*f0.z + f0.w*f0.w;
    sf += f1.x*f1.x + f1.y*f1.y + f1.z*f1.z + f1.w*f1.w;
    r = fmaf(g0.x - f0.x, m0, f0.x); su = fmaf(r, r, su);
    r = fmaf(g0.y - f0.y, m0, f0.y); su = fmaf(r, r, su);
    r = fmaf(g0.z - f0.z, m0, f0.z); su = fmaf(r, r, su);
    r = fmaf(g0.w - f0.w, m0, f0.w); su = fmaf(r, r, su);
    r = fmaf(g1.x - f1.x, m0, f1.x); su = fmaf(r, r, su);
    r = fmaf(g1.y - f1.y, m0, f1.y); su = fmaf(r, r, su);
    r = fmaf(g1.z - f1.z, m0, f1.z); su = fmaf(r, r, su);
    r = fmaf(g1.w - f1.w, m0, f1.w); su = fmaf(r, r, su);

    #pragma unroll
    for (int off = 32; off > 0; off >>= 1) {
        sf += __shfl_down(sf, off);
        su += __shfl_down(su, off);
    }
    if ((threadIdx.x & 63) == 0) {
        const int wid = tid >> 6;
        wave_sf[wid] = sf;
        wave_su[wid] = su;
    }
}

__global__ void ecli_reduce1(const float* __restrict__ wave_sf,
                             const float* __restrict__ wave_su,
                             double* __restrict__ part2_sf,
                             double* __restrict__ part2_su) {
    const int t = threadIdx.x;   // 256
    const int base = blockIdx.x * 256;
    double a = (double)wave_sf[base + t];
    double b = (double)wave_su[base + t];
    __shared__ double sa[4], sb[4];
    #pragma unroll
    for (int off = 32; off > 0; off >>= 1) {
        a += __shfl_down(a, off);
        b += __shfl_down(b, off);
    }
    if ((t & 63) == 0) { sa[t >> 6] = a; sb[t >> 6] = b; }
    __syncthreads();
    if (t == 0) {
        part2_sf[blockIdx.x] = sa[0] + sa[1] + sa[2] + sa[3];
        part2_su[blockIdx.x] = sb[0] + sb[1] + sb[2] + sb[3];
    }
}

__global__ void ecli_reduce2(const double* __restrict__ part2_sf,
                             const double* __restrict__ part2_su,
                             const double* __restrict__ fix_delta,
                             float* __restrict__ scale_out) {
    const int t = threadIdx.x;   // 256
    double a = 0.0, b = 0.0;
    if (t < RB1) { a = part2_sf[t]; b = part2_su[t]; }
    b += fix_delta[t];
    __shared__ double sa[4], sb[4];
    #pragma unroll
    for (int off = 32; off > 0; off >>= 1) {
        a += __shfl_down(a, off);
        b += __shfl_down(b, off);
    }
    if ((t & 63) == 0) { sa[t >> 6] = a; sb[t >> 6] = b; }
    __syncthreads();
    if (t == 0) {
        const double ta = sa[0] + sa[1] + sa[2] + sa[3];
        const double tb = sb[0] + sb[1] + sb[2] + sb[3];
        *scale_out = (tb > 0.0) ? (float)sqrt(ta / tb) : 1.0f;
    }
}

__global__ void __launch_bounds__(TPB) ecli_write(
        const float* __restrict__ field,
        const float* __restrict__ signal,
        const float* __restrict__ gratio,
        const float* __restrict__ infl,
        const float* __restrict__ scale_ptr,
        float* __restrict__ out) {
    const int tid = blockIdx.x * TPB + threadIdx.x;
    const float gr = *gratio;
    const float is = *infl;
    const float m0 = is / (1.0f + expf(-gr));
    const float scale = *scale_ptr;
    const float4* __restrict__ F = (const float4*)field;
    const float4* __restrict__ G = (const float4*)signal;
    vfloat4* __restrict__ O = (vfloat4*)out;

    float4 f0 = F[tid];
    float4 f1 = F[tid + NT];
    float4 g0 = G[tid];
    float4 g1 = G[tid + NT];

    vfloat4 v;
    float t_;
    t_ = fmaf(g0.x - f0.x, m0, f0.x); v.x = t_ * scale;
    t_ = fmaf(g0.y - f0.y, m0, f0.y); v.y = t_ * scale;
    t_ = fmaf(g0.z - f0.z, m0, f0.z); v.z = t_ * scale;
    t_ = fmaf(g0.w - f0.w, m0, f0.w); v.w = t_ * scale;
    __builtin_nontemporal_store(v, &O[tid]);
    t_ = fmaf(g1.x - f1.x, m0, f1.x); v.x = t_ * scale;
    t_ = fmaf(g1.y - f1.y, m0, f1.y); v.y = t_ * scale;
    t_ = fmaf(g1.z - f1.z, m0, f1.z); v.z = t_ * scale;
    t_ = fmaf(g1.w - f1.w, m0, f1.w); v.w = t_ * scale;
    __builtin_nontemporal_store(v, &O[tid + NT]);
}

__global__ void ecli_apply(const int* __restrict__ list_idx,
                           const float* __restrict__ list_fu,
                           const float* __restrict__ scale_ptr,
                           float* __restrict__ out) {
    const int tid = blockIdx.x * blockDim.x + threadIdx.x;
    if (tid >= MAXTOUCH) return;
    const int idx = list_idx[tid];
    if (idx < 0) return;
    out[idx] = list_fu[tid] * (*scale_ptr);
}

extern "C" void kernel_launch(void* const* d_in, const int* in_sizes, int n_in,
                              void* d_out, int out_size, void* d_ws, size_t ws_size,
                              hipStream_t stream) {
    const float* field    = (const float*)d_in[0];
    const float* signal   = (const float*)d_in[1];
    const int*   pos      = (const int*)d_in[2];
    const float* strength = (const float*)d_in[3];
    const float* infl     = (const float*)d_in[4];
    const float* gratio   = (const float*)d_in[5];
    const float* lratio   = (const float*)d_in[6];
    float* out = (float*)d_out;

    char* ws = (char*)d_ws;
    double* fix_delta = (double*)(ws + FIX_OFF);
    double* part2_sf  = (double*)(ws + P2SF_OFF);
    double* part2_su  = (double*)(ws + P2SU_OFF);
    float*  scale_ptr = (float*)(ws + SCALE_OFF);
    float*  wave_sf   = (float*)(ws + WSF_OFF);
    float*  wave_su   = (float*)(ws + WSU_OFF);
    int*    list_idx  = (int*)(ws + LIDX_OFF);
    float*  list_fu   = (float*)(ws + LFU_OFF);

    // ---- diagnostic probes (sinks fully overwritten by norms2 below) ----
    probe_null <<<NB,  TPB, 0, stream>>>(wave_sf);
    probe_f    <<<NB,  TPB, 0, stream>>>(field, wave_sf);
    probe_shift<<<NB,  TPB, 0, stream>>>(field, signal, wave_su);
    probe_gs   <<<GSB, TPB, 0, stream>>>(field, signal, wave_sf);

    // ---- real pipeline (identical to R8) ----
    ecli_clear  <<<KK, 448, 0, stream>>>(pos, out);
    ecli_scatter<<<KK, 448, 0, stream>>>(pos, strength, lratio, out);
    ecli_fixup  <<<KK, 448, 0, stream>>>(pos, field, signal, gratio, infl,
                                         out, list_idx, list_fu, fix_delta);
    ecli_norms2 <<<NB, TPB, 0, stream>>>(field, signal, gratio, infl,
                                         wave_sf, wave_su);
    ecli_reduce1<<<RB1, 256, 0, stream>>>(wave_sf, wave_su, part2_sf, part2_su);
    ecli_reduce2<<<1, 256, 0, stream>>>(part2_sf, part2_su, fix_delta, scale_ptr);
    ecli_write  <<<NB, TPB, 0, stream>>>(field, signal, gratio, infl,
                                         scale_ptr, out);
    ecli_apply  <<<(MAXTOUCH + 255) / 256, 256, 0, stream>>>(list_idx, list_fu,
                                                             scale_ptr, out);
}

// Round 10
// 82.903 us; speedup vs baseline: 1.5103x; 1.5103x over previous
//
#include <hip/hip_runtime.h>

#define HH 4096
#define WW 4096
#define KK 256
#define RMAX 10
#define DD 21
#define NSQ (DD * DD)              // 441
#define MAXTOUCH (KK * NSQ)        // 112896

#define NB  8192                   // blocks for dense kernels
#define TPB 256
#define NT  (NB * TPB)             // 2097152 threads; 2 float4 per stream each
#define RB1 2048                   // reduce stage-1 blocks (1024 partials each)

typedef float vfloat4 __attribute__((ext_vector_type(4)));

// d_ws layout (bytes):
#define FIX_OFF   0                      // double fix_delta[KK]        (2048 B)
#define SCALE_OFF 4096                   // float  scale
#define P2FF_OFF  8192                   // double part2_ff[RB1]        (16384 B)
#define P2FG_OFF  (8192 + 16384)         // double part2_fg[RB1]        (16384 B)
#define P2GG_OFF  (8192 + 32768)         // double part2_gg[RB1]        (16384 B)
#define LIDX_OFF  65536                  // int    list_idx[MAXTOUCH]   (451584 B)
#define LFU_OFF   (65536 + 451584)       // float  list_fu[MAXTOUCH]    (451584 B)
#define TPFF_OFF  (1 << 20)              // float  tp_ff[NT]            (8 MB)
#define TPFG_OFF  ((1 << 20) + (NT * 4))       // float tp_fg[NT]       (8 MB)
#define TPGG_OFF  ((1 << 20) + 2 * (NT * 4))   // float tp_gg[NT]       (8 MB)

// K0: zero the 21x21 in-bounds square of every attractor in the addmap.
// addmap lives in d_out (stale output during replays; overwritten later).
__global__ void ecli_clear(const int* __restrict__ pos, float* __restrict__ addmap) {
    const int k = blockIdx.x;
    const int t = threadIdx.x;
    if (t >= NSQ) return;
    const int ni = pos[2 * k + 0] + t / DD - RMAX;
    const int nj = pos[2 * k + 1] + t % DD - RMAX;
    if (ni < 0 || ni >= HH || nj < 0 || nj >= WW) return;
    addmap[(size_t)ni * WW + nj] = 0.0f;
}

// K1: scatter-add attractor contributions (f32 atomics, uncontended).
__global__ void ecli_scatter(const int* __restrict__ pos,
                             const float* __restrict__ strength,
                             const float* __restrict__ local_ratio,
                             float* __restrict__ addmap) {
    const int k = blockIdx.x;
    const int t = threadIdx.x;
    if (t >= NSQ) return;
    const float s   = strength[k];
    const float lr  = *local_ratio;
    const float rad = floorf(5.0f * s);
    const float inv = -0.5f / (4.0f * s * s);
    const float amp = lr * s;
    const int di = t / DD - RMAX;
    const int dj = t % DD - RMAX;
    if (fabsf((float)di) > rad || fabsf((float)dj) > rad) return;
    const int ni = pos[2 * k + 0] + di;
    const int nj = pos[2 * k + 1] + dj;
    if (ni < 0 || ni >= HH || nj < 0 || nj >= WW) return;
    const float c = expf((float)(di * di + dj * dj) * inv) * amp;
    atomicAdd(&addmap[(size_t)ni * WW + nj], c);
}

// K2: claim each touched pixel once (atomicExch->0), write (idx, fu1) into
// deterministic slot, block-reduce the su-correction into fix_delta[k].
__global__ void ecli_fixup(const int* __restrict__ pos,
                           const float* __restrict__ field,
                           const float* __restrict__ signal,
                           const float* __restrict__ gratio,
                           const float* __restrict__ infl,
                           float* __restrict__ addmap,
                           int* __restrict__ list_idx,
                           float* __restrict__ list_fu,
                           double* __restrict__ fix_delta) {
    const int k = blockIdx.x;
    const int t = threadIdx.x;
    double delta = 0.0;
    if (t < NSQ) {
        int out_idx = -1;
        float out_fu = 0.0f;
        const int ni = pos[2 * k + 0] + t / DD - RMAX;
        const int nj = pos[2 * k + 1] + t % DD - RMAX;
        if (ni >= 0 && ni < HH && nj >= 0 && nj < WW) {
            const size_t idx = (size_t)ni * WW + nj;
            const float val = atomicExch(&addmap[idx], 0.0f);
            if (val != 0.0f) {
                const float gr = *gratio;
                const float is = *infl;
                const float f = field[idx];
                const float g = signal[idx];
                const float m0 = is / (1.0f + expf(-gr));
                const float m1 = is / (1.0f + expf(-(gr + val)));
                const float fu0 = fmaf(g - f, m0, f);
                const float fu1 = fmaf(g - f, m1, f);
                out_idx = (int)idx;
                out_fu  = fu1;
                delta = (double)fu1 * (double)fu1 - (double)fu0 * (double)fu0;
            }
        }
        list_idx[k * NSQ + t] = out_idx;
        list_fu [k * NSQ + t] = out_fu;
    }
    __shared__ double sred[7];
    #pragma unroll
    for (int off = 32; off > 0; off >>= 1) delta += __shfl_down(delta, off);
    if ((t & 63) == 0) sred[t >> 6] = delta;
    __syncthreads();
    if (t == 0) {
        double d = 0.0;
        #pragma unroll
        for (int i = 0; i < 7; ++i) d += sred[i];
        fix_delta[k] = d;
    }
}

// K3: moment sums ONLY — probe-shaped. No scalar param loads, no expf,
// no shuffles, no LDS. Per-thread Sff, Sfg, Sgg -> 3 planar f32 stores.
// (Sfu^2 is reconstructed algebraically in reduce2.)
__global__ void __launch_bounds__(TPB) ecli_norms3(
        const float* __restrict__ field,
        const float* __restrict__ signal,
        float* __restrict__ tp_ff,
        float* __restrict__ tp_fg,
        float* __restrict__ tp_gg) {
    const int tid = blockIdx.x * TPB + threadIdx.x;
    const float4* __restrict__ F = (const float4*)field;
    const float4* __restrict__ G = (const float4*)signal;

    float4 f0 = F[tid];
    float4 f1 = F[tid + NT];
    float4 g0 = G[tid];
    float4 g1 = G[tid + NT];

    float sff = 0.0f, sfg = 0.0f, sgg = 0.0f;
    sff = fmaf(f0.x, f0.x, sff); sfg = fmaf(f0.x, g0.x, sfg); sgg = fmaf(g0.x, g0.x, sgg);
    sff = fmaf(f0.y, f0.y, sff); sfg = fmaf(f0.y, g0.y, sfg); sgg = fmaf(g0.y, g0.y, sgg);
    sff = fmaf(f0.z, f0.z, sff); sfg = fmaf(f0.z, g0.z, sfg); sgg = fmaf(g0.z, g0.z, sgg);
    sff = fmaf(f0.w, f0.w, sff); sfg = fmaf(f0.w, g0.w, sfg); sgg = fmaf(g0.w, g0.w, sgg);
    sff = fmaf(f1.x, f1.x, sff); sfg = fmaf(f1.x, g1.x, sfg); sgg = fmaf(g1.x, g1.x, sgg);
    sff = fmaf(f1.y, f1.y, sff); sfg = fmaf(f1.y, g1.y, sfg); sgg = fmaf(g1.y, g1.y, sgg);
    sff = fmaf(f1.z, f1.z, sff); sfg = fmaf(f1.z, g1.z, sfg); sgg = fmaf(g1.z, g1.z, sgg);
    sff = fmaf(f1.w, f1.w, sff); sfg = fmaf(f1.w, g1.w, sfg); sgg = fmaf(g1.w, g1.w, sgg);

    tp_ff[tid] = sff;
    tp_fg[tid] = sfg;
    tp_gg[tid] = sgg;
}

// K4a: stage-1 reduce of thread partials (24 MB, L2/L3-hot). 2048 blocks.
__global__ void __launch_bounds__(256) ecli_reduce1(
        const float* __restrict__ tp_ff,
        const float* __restrict__ tp_fg,
        const float* __restrict__ tp_gg,
        double* __restrict__ part2_ff,
        double* __restrict__ part2_fg,
        double* __restrict__ part2_gg) {
    const int t = threadIdx.x;
    const int base = blockIdx.x * 1024 + t;
    double a = 0.0, b = 0.0, c = 0.0;
    #pragma unroll
    for (int k = 0; k < 4; ++k) {
        a += (double)tp_ff[base + k * 256];
        b += (double)tp_fg[base + k * 256];
        c += (double)tp_gg[base + k * 256];
    }
    __shared__ double sa[4], sb[4], sc[4];
    #pragma unroll
    for (int off = 32; off > 0; off >>= 1) {
        a += __shfl_down(a, off);
        b += __shfl_down(b, off);
        c += __shfl_down(c, off);
    }
    if ((t & 63) == 0) { sa[t >> 6] = a; sb[t >> 6] = b; sc[t >> 6] = c; }
    __syncthreads();
    if (t == 0) {
        part2_ff[blockIdx.x] = sa[0] + sa[1] + sa[2] + sa[3];
        part2_fg[blockIdx.x] = sb[0] + sb[1] + sb[2] + sb[3];
        part2_gg[blockIdx.x] = sc[0] + sc[1] + sc[2] + sc[3];
    }
}

// K4b: final reduce + algebraic Sfu^2 + scale.
__global__ void ecli_reduce2(const double* __restrict__ part2_ff,
                             const double* __restrict__ part2_fg,
                             const double* __restrict__ part2_gg,
                             const double* __restrict__ fix_delta,
                             const float* __restrict__ gratio,
                             const float* __restrict__ infl,
                             float* __restrict__ scale_out) {
    const int t = threadIdx.x;   // 1024
    double a = part2_ff[t] + part2_ff[t + 1024];
    double b = part2_fg[t] + part2_fg[t + 1024];
    double c = part2_gg[t] + part2_gg[t + 1024];
    double d = (t < KK) ? fix_delta[t] : 0.0;
    __shared__ double sa[16], sb[16], sc[16], sd[16];
    #pragma unroll
    for (int off = 32; off > 0; off >>= 1) {
        a += __shfl_down(a, off);
        b += __shfl_down(b, off);
        c += __shfl_down(c, off);
        d += __shfl_down(d, off);
    }
    if ((t & 63) == 0) { sa[t >> 6] = a; sb[t >> 6] = b; sc[t >> 6] = c; sd[t >> 6] = d; }
    __syncthreads();
    if (t == 0) {
        double tff = 0.0, tfg = 0.0, tgg = 0.0, tfix = 0.0;
        #pragma unroll
        for (int i = 0; i < 16; ++i) {
            tff += sa[i]; tfg += sb[i]; tgg += sc[i]; tfix += sd[i];
        }
        const float gr = *gratio;
        const float is = *infl;
        const double m0 = (double)(is / (1.0f + expf(-gr)));
        const double om = 1.0 - m0;
        const double tb = om * om * tff + 2.0 * m0 * om * tfg + m0 * m0 * tgg + tfix;
        *scale_out = (tb > 0.0) ? (float)sqrt(tff / tb) : 1.0f;
    }
}

// K5: out = (f + (g-f)*m0) * scale; nontemporal stores.
__global__ void __launch_bounds__(TPB) ecli_write(
        const float* __restrict__ field,
        const float* __restrict__ signal,
        const float* __restrict__ gratio,
        const float* __restrict__ infl,
        const float* __restrict__ scale_ptr,
        float* __restrict__ out) {
    const int tid = blockIdx.x * TPB + threadIdx.x;
    const float gr = *gratio;
    const float is = *infl;
    const float m0 = is / (1.0f + expf(-gr));
    const float scale = *scale_ptr;
    const float4* __restrict__ F = (const float4*)field;
    const float4* __restrict__ G = (const float4*)signal;
    vfloat4* __restrict__ O = (vfloat4*)out;

    float4 f0 = F[tid];
    float4 f1 = F[tid + NT];
    float4 g0 = G[tid];
    float4 g1 = G[tid + NT];

    vfloat4 v;
    float t_;
    t_ = fmaf(g0.x - f0.x, m0, f0.x); v.x = t_ * scale;
    t_ = fmaf(g0.y - f0.y, m0, f0.y); v.y = t_ * scale;
    t_ = fmaf(g0.z - f0.z, m0, f0.z); v.z = t_ * scale;
    t_ = fmaf(g0.w - f0.w, m0, f0.w); v.w = t_ * scale;
    __builtin_nontemporal_store(v, &O[tid]);
    t_ = fmaf(g1.x - f1.x, m0, f1.x); v.x = t_ * scale;
    t_ = fmaf(g1.y - f1.y, m0, f1.y); v.y = t_ * scale;
    t_ = fmaf(g1.z - f1.z, m0, f1.z); v.z = t_ * scale;
    t_ = fmaf(g1.w - f1.w, m0, f1.w); v.w = t_ * scale;
    __builtin_nontemporal_store(v, &O[tid + NT]);
}

// K6: apply sparse corrections, scaled.
__global__ void ecli_apply(const int* __restrict__ list_idx,
                           const float* __restrict__ list_fu,
                           const float* __restrict__ scale_ptr,
                           float* __restrict__ out) {
    const int tid = blockIdx.x * blockDim.x + threadIdx.x;
    if (tid >= MAXTOUCH) return;
    const int idx = list_idx[tid];
    if (idx < 0) return;
    out[idx] = list_fu[tid] * (*scale_ptr);
}

extern "C" void kernel_launch(void* const* d_in, const int* in_sizes, int n_in,
                              void* d_out, int out_size, void* d_ws, size_t ws_size,
                              hipStream_t stream) {
    const float* field    = (const float*)d_in[0];
    const float* signal   = (const float*)d_in[1];
    const int*   pos      = (const int*)d_in[2];
    const float* strength = (const float*)d_in[3];
    const float* infl     = (const float*)d_in[4];
    const float* gratio   = (const float*)d_in[5];
    const float* lratio   = (const float*)d_in[6];
    float* out = (float*)d_out;

    char* ws = (char*)d_ws;
    double* fix_delta = (double*)(ws + FIX_OFF);
    float*  scale_ptr = (float*)(ws + SCALE_OFF);
    double* part2_ff  = (double*)(ws + P2FF_OFF);
    double* part2_fg  = (double*)(ws + P2FG_OFF);
    double* part2_gg  = (double*)(ws + P2GG_OFF);
    int*    list_idx  = (int*)(ws + LIDX_OFF);
    float*  list_fu   = (float*)(ws + LFU_OFF);
    float*  tp_ff     = (float*)(ws + TPFF_OFF);
    float*  tp_fg     = (float*)(ws + TPFG_OFF);
    float*  tp_gg     = (float*)(ws + TPGG_OFF);

    ecli_clear  <<<KK, 448, 0, stream>>>(pos, out);
    ecli_scatter<<<KK, 448, 0, stream>>>(pos, strength, lratio, out);
    ecli_fixup  <<<KK, 448, 0, stream>>>(pos, field, signal, gratio, infl,
                                         out, list_idx, list_fu, fix_delta);
    ecli_norms3 <<<NB, TPB, 0, stream>>>(field, signal, tp_ff, tp_fg, tp_gg);
    ecli_reduce1<<<RB1, 256, 0, stream>>>(tp_ff, tp_fg, tp_gg,
                                          part2_ff, part2_fg, part2_gg);
    ecli_reduce2<<<1, 1024, 0, stream>>>(part2_ff, part2_fg, part2_gg,
                                         fix_delta, gratio, infl, scale_ptr);
    ecli_write  <<<NB, TPB, 0, stream>>>(field, signal, gratio, infl,
                                         scale_ptr, out);
    ecli_apply  <<<(MAXTOUCH + 255) / 256, 256, 0, stream>>>(list_idx, list_fu,
                                                             scale_ptr, out);
}

// Round 11
// 73.939 us; speedup vs baseline: 1.6934x; 1.1212x over previous
//
#include <hip/hip_runtime.h>

#define HH 4096
#define WW 4096
#define KK 256
#define RMAX 10
#define DD 21
#define NSQ (DD * DD)              // 441
#define MAXTOUCH (KK * NSQ)        // 112896

#define NB  8192                   // blocks for ecli_write
#define TPB 256
#define NT  (NB * TPB)             // float4 slots per half-stream for write
#define GSB 2048                   // grid-stride blocks for norms4
#define GST (GSB * TPB)            // 524288 threads, 8 float4-pairs each
#define NW4 (GST / 64)             // 8192 waves

typedef float vfloat4 __attribute__((ext_vector_type(4)));

// d_ws layout (bytes):
#define FIX_OFF   0                      // double fix_delta[KK]     (2048 B)
#define SCALE_OFF 4096                   // float  scale
#define WFF_OFF   8192                   // float  wave_ff[NW4]      (32768 B)
#define WFG_OFF   (8192 + 32768)         // float  wave_fg[NW4]      (32768 B)
#define WGG_OFF   (8192 + 65536)         // float  wave_gg[NW4]      (32768 B)
#define LIDX_OFF  (8192 + 98304)         // int    list_idx[MAXTOUCH]
#define LFU_OFF   (LIDX_OFF + 451584)    // float  list_fu[MAXTOUCH]

// K0: zero the 21x21 in-bounds square of every attractor in the addmap.
// addmap lives in d_out (stale output during replays; overwritten later).
__global__ void ecli_clear(const int* __restrict__ pos, float* __restrict__ addmap) {
    const int k = blockIdx.x;
    const int t = threadIdx.x;
    if (t >= NSQ) return;
    const int ni = pos[2 * k + 0] + t / DD - RMAX;
    const int nj = pos[2 * k + 1] + t % DD - RMAX;
    if (ni < 0 || ni >= HH || nj < 0 || nj >= WW) return;
    addmap[(size_t)ni * WW + nj] = 0.0f;
}

// K1: scatter-add attractor contributions (f32 atomics, uncontended).
__global__ void ecli_scatter(const int* __restrict__ pos,
                             const float* __restrict__ strength,
                             const float* __restrict__ local_ratio,
                             float* __restrict__ addmap) {
    const int k = blockIdx.x;
    const int t = threadIdx.x;
    if (t >= NSQ) return;
    const float s   = strength[k];
    const float lr  = *local_ratio;
    const float rad = floorf(5.0f * s);
    const float inv = -0.5f / (4.0f * s * s);
    const float amp = lr * s;
    const int di = t / DD - RMAX;
    const int dj = t % DD - RMAX;
    if (fabsf((float)di) > rad || fabsf((float)dj) > rad) return;
    const int ni = pos[2 * k + 0] + di;
    const int nj = pos[2 * k + 1] + dj;
    if (ni < 0 || ni >= HH || nj < 0 || nj >= WW) return;
    const float c = expf((float)(di * di + dj * dj) * inv) * amp;
    atomicAdd(&addmap[(size_t)ni * WW + nj], c);
}

// K2: claim each touched pixel once (atomicExch->0), write (idx, fu1) into
// deterministic slot, block-reduce the su-correction into fix_delta[k].
__global__ void ecli_fixup(const int* __restrict__ pos,
                           const float* __restrict__ field,
                           const float* __restrict__ signal,
                           const float* __restrict__ gratio,
                           const float* __restrict__ infl,
                           float* __restrict__ addmap,
                           int* __restrict__ list_idx,
                           float* __restrict__ list_fu,
                           double* __restrict__ fix_delta) {
    const int k = blockIdx.x;
    const int t = threadIdx.x;
    double delta = 0.0;
    if (t < NSQ) {
        int out_idx = -1;
        float out_fu = 0.0f;
        const int ni = pos[2 * k + 0] + t / DD - RMAX;
        const int nj = pos[2 * k + 1] + t % DD - RMAX;
        if (ni >= 0 && ni < HH && nj >= 0 && nj < WW) {
            const size_t idx = (size_t)ni * WW + nj;
            const float val = atomicExch(&addmap[idx], 0.0f);
            if (val != 0.0f) {
                const float gr = *gratio;
                const float is = *infl;
                const float f = field[idx];
                const float g = signal[idx];
                const float m0 = is / (1.0f + expf(-gr));
                const float m1 = is / (1.0f + expf(-(gr + val)));
                const float fu0 = fmaf(g - f, m0, f);
                const float fu1 = fmaf(g - f, m1, f);
                out_idx = (int)idx;
                out_fu  = fu1;
                delta = (double)fu1 * (double)fu1 - (double)fu0 * (double)fu0;
            }
        }
        list_idx[k * NSQ + t] = out_idx;
        list_fu [k * NSQ + t] = out_fu;
    }
    __shared__ double sred[7];
    #pragma unroll
    for (int off = 32; off > 0; off >>= 1) delta += __shfl_down(delta, off);
    if ((t & 63) == 0) sred[t >> 6] = delta;
    __syncthreads();
    if (t == 0) {
        double d = 0.0;
        #pragma unroll
        for (int i = 0; i < 7; ++i) d += sred[i];
        fix_delta[k] = d;
    }
}

// K3: moment sums in the PROVEN-FAST probe_gs shape: 2048 blocks,
// grid-stride 8 iters, one paired {F[i],G[i]} load per iter.
// Only delta vs probe_gs: 3 accumulator chains instead of 1.
__global__ void __launch_bounds__(TPB) ecli_norms4(
        const float* __restrict__ field,
        const float* __restrict__ signal,
        float* __restrict__ wave_ff,
        float* __restrict__ wave_fg,
        float* __restrict__ wave_gg) {
    const int tid0 = blockIdx.x * TPB + threadIdx.x;
    const float4* __restrict__ F = (const float4*)field;
    const float4* __restrict__ G = (const float4*)signal;
    float sff = 0.0f, sfg = 0.0f, sgg = 0.0f;
    for (int i = tid0; i < HH * WW / 4; i += GST) {
        float4 f = F[i];
        float4 g = G[i];
        sff = fmaf(f.x, f.x, sff); sfg = fmaf(f.x, g.x, sfg); sgg = fmaf(g.x, g.x, sgg);
        sff = fmaf(f.y, f.y, sff); sfg = fmaf(f.y, g.y, sfg); sgg = fmaf(g.y, g.y, sgg);
        sff = fmaf(f.z, f.z, sff); sfg = fmaf(f.z, g.z, sfg); sgg = fmaf(g.z, g.z, sgg);
        sff = fmaf(f.w, f.w, sff); sfg = fmaf(f.w, g.w, sfg); sgg = fmaf(g.w, g.w, sgg);
    }
    #pragma unroll
    for (int off = 32; off > 0; off >>= 1) {
        sff += __shfl_down(sff, off);
        sfg += __shfl_down(sfg, off);
        sgg += __shfl_down(sgg, off);
    }
    if ((threadIdx.x & 63) == 0) {
        const int wid = tid0 >> 6;
        wave_ff[wid] = sff;
        wave_fg[wid] = sfg;
        wave_gg[wid] = sgg;
    }
}

// K4: single-block final reduce (8192x3 f32 partials + 256 fix doubles)
// + algebraic Sfu^2 + scale.
__global__ void ecli_reduce(const float* __restrict__ wave_ff,
                            const float* __restrict__ wave_fg,
                            const float* __restrict__ wave_gg,
                            const double* __restrict__ fix_delta,
                            const float* __restrict__ gratio,
                            const float* __restrict__ infl,
                            float* __restrict__ scale_out) {
    const int t = threadIdx.x;   // 1024
    double a = 0.0, b = 0.0, c = 0.0;
    #pragma unroll
    for (int k = 0; k < 8; ++k) {
        const int idx = t + k * 1024;
        a += (double)wave_ff[idx];
        b += (double)wave_fg[idx];
        c += (double)wave_gg[idx];
    }
    double d = (t < KK) ? fix_delta[t] : 0.0;
    __shared__ double sa[16], sb[16], sc[16], sd[16];
    #pragma unroll
    for (int off = 32; off > 0; off >>= 1) {
        a += __shfl_down(a, off);
        b += __shfl_down(b, off);
        c += __shfl_down(c, off);
        d += __shfl_down(d, off);
    }
    if ((t & 63) == 0) { sa[t >> 6] = a; sb[t >> 6] = b; sc[t >> 6] = c; sd[t >> 6] = d; }
    __syncthreads();
    if (t == 0) {
        double tff = 0.0, tfg = 0.0, tgg = 0.0, tfix = 0.0;
        #pragma unroll
        for (int i = 0; i < 16; ++i) {
            tff += sa[i]; tfg += sb[i]; tgg += sc[i]; tfix += sd[i];
        }
        const float gr = *gratio;
        const float is = *infl;
        const double m0 = (double)(is / (1.0f + expf(-gr)));
        const double om = 1.0 - m0;
        const double tb = om * om * tff + 2.0 * m0 * om * tfg + m0 * m0 * tgg + tfix;
        *scale_out = (tb > 0.0) ? (float)sqrt(tff / tb) : 1.0f;
    }
}

// K5: out = (f + (g-f)*m0) * scale; nontemporal stores. (unchanged, ~15us)
__global__ void __launch_bounds__(TPB) ecli_write(
        const float* __restrict__ field,
        const float* __restrict__ signal,
        const float* __restrict__ gratio,
        const float* __restrict__ infl,
        const float* __restrict__ scale_ptr,
        float* __restrict__ out) {
    const int tid = blockIdx.x * TPB + threadIdx.x;
    const float gr = *gratio;
    const float is = *infl;
    const float m0 = is / (1.0f + expf(-gr));
    const float scale = *scale_ptr;
    const float4* __restrict__ F = (const float4*)field;
    const float4* __restrict__ G = (const float4*)signal;
    vfloat4* __restrict__ O = (vfloat4*)out;

    float4 f0 = F[tid];
    float4 f1 = F[tid + NT];
    float4 g0 = G[tid];
    float4 g1 = G[tid + NT];

    vfloat4 v;
    float t_;
    t_ = fmaf(g0.x - f0.x, m0, f0.x); v.x = t_ * scale;
    t_ = fmaf(g0.y - f0.y, m0, f0.y); v.y = t_ * scale;
    t_ = fmaf(g0.z - f0.z, m0, f0.z); v.z = t_ * scale;
    t_ = fmaf(g0.w - f0.w, m0, f0.w); v.w = t_ * scale;
    __builtin_nontemporal_store(v, &O[tid]);
    t_ = fmaf(g1.x - f1.x, m0, f1.x); v.x = t_ * scale;
    t_ = fmaf(g1.y - f1.y, m0, f1.y); v.y = t_ * scale;
    t_ = fmaf(g1.z - f1.z, m0, f1.z); v.z = t_ * scale;
    t_ = fmaf(g1.w - f1.w, m0, f1.w); v.w = t_ * scale;
    __builtin_nontemporal_store(v, &O[tid + NT]);
}

// K6: apply sparse corrections, scaled.
__global__ void ecli_apply(const int* __restrict__ list_idx,
                           const float* __restrict__ list_fu,
                           const float* __restrict__ scale_ptr,
                           float* __restrict__ out) {
    const int tid = blockIdx.x * blockDim.x + threadIdx.x;
    if (tid >= MAXTOUCH) return;
    const int idx = list_idx[tid];
    if (idx < 0) return;
    out[idx] = list_fu[tid] * (*scale_ptr);
}

extern "C" void kernel_launch(void* const* d_in, const int* in_sizes, int n_in,
                              void* d_out, int out_size, void* d_ws, size_t ws_size,
                              hipStream_t stream) {
    const float* field    = (const float*)d_in[0];
    const float* signal   = (const float*)d_in[1];
    const int*   pos      = (const int*)d_in[2];
    const float* strength = (const float*)d_in[3];
    const float* infl     = (const float*)d_in[4];
    const float* gratio   = (const float*)d_in[5];
    const float* lratio   = (const float*)d_in[6];
    float* out = (float*)d_out;

    char* ws = (char*)d_ws;
    double* fix_delta = (double*)(ws + FIX_OFF);
    float*  scale_ptr = (float*)(ws + SCALE_OFF);
    float*  wave_ff   = (float*)(ws + WFF_OFF);
    float*  wave_fg   = (float*)(ws + WFG_OFF);
    float*  wave_gg   = (float*)(ws + WGG_OFF);
    int*    list_idx  = (int*)(ws + LIDX_OFF);
    float*  list_fu   = (float*)(ws + LFU_OFF);

    ecli_clear  <<<KK, 448, 0, stream>>>(pos, out);
    ecli_scatter<<<KK, 448, 0, stream>>>(pos, strength, lratio, out);
    ecli_fixup  <<<KK, 448, 0, stream>>>(pos, field, signal, gratio, infl,
                                         out, list_idx, list_fu, fix_delta);
    ecli_norms4 <<<GSB, TPB, 0, stream>>>(field, signal,
                                          wave_ff, wave_fg, wave_gg);
    ecli_reduce <<<1, 1024, 0, stream>>>(wave_ff, wave_fg, wave_gg,
                                         fix_delta, gratio, infl, scale_ptr);
    ecli_write  <<<NB, TPB, 0, stream>>>(field, signal, gratio, infl,
                                         scale_ptr, out);
    ecli_apply  <<<(MAXTOUCH + 255) / 256, 256, 0, stream>>>(list_idx, list_fu,
                                                             scale_ptr, out);
}